// Round 2
// baseline (375.194 us; speedup 1.0000x reference)
//
#include <hip/hip_runtime.h>
#include <cstdint>
#include <cstddef>

// L1 attention scores on MI355X.
// out[b,s,t,h] = -(1/sqrt(D)) * sum_d |q[b,s,h,d] - k[b,t,h,d]|
// B=2, S=2048, H=8, D=32, fp32.
//
// Structure (round 2: synchronous staging — async global_load_lds with two
// different LDS bases per wave is the suspected M0 hazard from round 1):
//  - grid = B * (S/16) * 4 = 1024 blocks, 256 threads (4 waves).
//  - block handles: one b, 16 s-values (4 per wave), one quarter of t.
//  - lane -> (t_sub = lane>>3, h = lane&7) within an 8-t chunk.
//  - q[b, s_i, h, :] (4 rows x 32 floats) pinned in VGPRs for block lifetime.
//  - k streamed in 8-t chunks (8KB) through a single LDS buffer; register
//    pair (st0,st1) holds the next chunk (double-buffer via registers).
//  - LDS layout is d-major transposed: float4-index F4 = dv*64 + row,
//    row = 8*t_sub + h. Both ds_write_b128 (staging) and ds_read_b128
//    (compute) are bank-uniform (8 words/bank, same as contiguous).

#define S_DIM 2048
#define H_DIM 8
#define D_DIM 32
#define RS 4          // s-values per thread (per wave)
#define SB 16         // s-values per block (4 waves * RS)
#define TSPLIT 4      // t-range split across blocks
#define TCHUNK 8      // t-values staged per LDS chunk
#define NTHREADS 256
#define NCH ((S_DIM / TSPLIT) / TCHUNK)   // 64 chunks

typedef float f32x4 __attribute__((ext_vector_type(4)));

__global__ __launch_bounds__(NTHREADS) void l1attn_kernel(
    const float* __restrict__ q, const float* __restrict__ k,
    float* __restrict__ out)
{
  // 2048 floats = 8 KB. F4 = dv*64 + row  <->  k[t_sub, h, d]:
  // row = 8*t_sub + h, dv = d>>2.
  __shared__ float ldsk[TCHUNK * H_DIM * D_DIM];

  const int tid  = threadIdx.x;
  const int lane = tid & 63;
  const int wave = tid >> 6;

  const int bid = blockIdx.x;
  const int b   = bid >> 9;          // 512 blocks per batch element
  const int rem = bid & 511;
  const int sg  = rem >> 2;          // s-group 0..127
  const int tq  = rem & 3;           // t-quarter 0..3

  const int h      = lane & 7;
  const int t_sub  = lane >> 3;
  const int s_base = sg * SB + wave * RS;
  const int t0     = tq * (S_DIM / TSPLIT);   // 512 * tq

  // ---- q fragments -> registers (128 VGPRs, held for whole block) ----
  f32x4 qf[RS][8];
  {
    const float* qb = q + (size_t)b * S_DIM * (H_DIM * D_DIM);
#pragma unroll
    for (int i = 0; i < RS; ++i) {
      const float* qr = qb + (size_t)(s_base + i) * (H_DIM * D_DIM) + h * D_DIM;
#pragma unroll
      for (int dv = 0; dv < 8; ++dv)
        qf[i][dv] = *(const f32x4*)(qr + dv * 4);
    }
  }

  const float* kb = k + (size_t)b * S_DIM * (H_DIM * D_DIM);

  // Staging map: global f32x4 index g4 = row*8 + dv (row=0..63, dv=0..7);
  // this thread stages g4 = tid and tid+256 (coalesced global reads).
  // LDS dest f32x4 index: F4 = dv*64 + row = (g4&7)*64 + (g4>>3).
  const int g4a = tid;
  const int g4b = tid + 256;
  const int f4a = (g4a & 7) * 64 + (g4a >> 3);
  const int f4b = (g4b & 7) * 64 + (g4b >> 3);

  // preload chunk 0 into registers
  const f32x4* kc0 = (const f32x4*)(kb + (size_t)t0 * (H_DIM * D_DIM));
  f32x4 st0 = kc0[g4a];
  f32x4 st1 = kc0[g4b];

  const float nscale = -0.17677669529663687f;  // -1/sqrt(32)
  float* optr = out +
      ((size_t)(b * S_DIM + s_base) * S_DIM + (size_t)(t0 + t_sub)) * H_DIM + h;

  f32x4* ldsv = (f32x4*)ldsk;

  for (int c = 0; c < NCH; ++c) {
    __syncthreads();   // all waves done reading LDS from previous iteration

    ldsv[f4a] = st0;   // ds_write_b128, bank-uniform
    ldsv[f4b] = st1;

    if (c + 1 < NCH) { // register-prefetch next chunk (global loads in flight)
      const f32x4* kn = (const f32x4*)(kb +
          (size_t)(t0 + (c + 1) * TCHUNK) * (H_DIM * D_DIM));
      st0 = kn[g4a];
      st1 = kn[g4b];
    }

    __syncthreads();   // staged chunk visible to all waves

    float acc0 = 0.f, acc1 = 0.f, acc2 = 0.f, acc3 = 0.f;
#pragma unroll
    for (int dv = 0; dv < 8; ++dv) {
      const f32x4 kf = ldsv[dv * 64 + lane];   // ds_read_b128, bank-uniform
      acc0 += __builtin_fabsf(qf[0][dv].x - kf.x) + __builtin_fabsf(qf[0][dv].y - kf.y)
            + __builtin_fabsf(qf[0][dv].z - kf.z) + __builtin_fabsf(qf[0][dv].w - kf.w);
      acc1 += __builtin_fabsf(qf[1][dv].x - kf.x) + __builtin_fabsf(qf[1][dv].y - kf.y)
            + __builtin_fabsf(qf[1][dv].z - kf.z) + __builtin_fabsf(qf[1][dv].w - kf.w);
      acc2 += __builtin_fabsf(qf[2][dv].x - kf.x) + __builtin_fabsf(qf[2][dv].y - kf.y)
            + __builtin_fabsf(qf[2][dv].z - kf.z) + __builtin_fabsf(qf[2][dv].w - kf.w);
      acc3 += __builtin_fabsf(qf[3][dv].x - kf.x) + __builtin_fabsf(qf[3][dv].y - kf.y)
            + __builtin_fabsf(qf[3][dv].z - kf.z) + __builtin_fabsf(qf[3][dv].w - kf.w);
    }

    // coalesced dword stores: consecutive lanes -> consecutive (t,h) addrs
    float* o = optr + (size_t)c * (TCHUNK * H_DIM);
    o[0]                         = acc0 * nscale;
    o[(size_t)1 * S_DIM * H_DIM] = acc1 * nscale;
    o[(size_t)2 * S_DIM * H_DIM] = acc2 * nscale;
    o[(size_t)3 * S_DIM * H_DIM] = acc3 * nscale;
  }
}

extern "C" void kernel_launch(void* const* d_in, const int* in_sizes, int n_in,
                              void* d_out, int out_size, void* d_ws, size_t ws_size,
                              hipStream_t stream) {
  const float* q = (const float*)d_in[0];
  const float* k = (const float*)d_in[1];
  float* out = (float*)d_out;
  const int B = 2;
  dim3 grid(B * (S_DIM / SB) * TSPLIT);   // 1024 blocks
  dim3 block(NTHREADS);
  l1attn_kernel<<<grid, block, 0, stream>>>(q, k, out);
}

// Round 3
// 351.340 us; speedup vs baseline: 1.0679x; 1.0679x over previous
//
#include <hip/hip_runtime.h>
#include <cstdint>
#include <cstddef>

// L1 attention scores on MI355X.
// out[b,s,t,h] = -(1/sqrt(D)) * sum_d |q[b,s,h,d] - k[b,t,h,d]|
// B=2, S=2048, H=8, D=32, fp32.
//
// Round 3 changes (from rocprof: 2.9e7 LDS bank conflicts = ~28% of cycles,
// occupancy 25%):
//  - Rotation-swizzled LDS layout: element (row,dv) lives at f32x4 index
//    f4 = row*8 + ((dv+row)&7). Staging writes permute within each 128 B
//    block (all 8 bank-quads per 8-lane group -> conflict-free); compute
//    reads use precomputed loop-invariant addresses, also one lane per
//    bank-quad per 8-lane group -> conflict-free.
//  - TSPLIT 4 -> 8: 2048 blocks (8/CU) for barrier/latency hiding.
//  - True LDS double-buffer with ONE barrier per chunk: after the barrier,
//    write next chunk (from prefetch regs) to buf^1 and compute from buf.

#define S_DIM 2048
#define H_DIM 8
#define D_DIM 32
#define RS 4          // s-values per thread (per wave)
#define SB 16         // s-values per block (4 waves * RS)
#define TSPLIT 8      // t-range split across blocks
#define TCHUNK 8      // t-values staged per LDS chunk
#define NTHREADS 256
#define NCH ((S_DIM / TSPLIT) / TCHUNK)   // 32 chunks of 8 t

typedef float f32x4 __attribute__((ext_vector_type(4)));

__global__ __launch_bounds__(NTHREADS) void l1attn_kernel(
    const float* __restrict__ q, const float* __restrict__ k,
    float* __restrict__ out)
{
  // Chunk element (t_sub, h, d): row = 8*t_sub + h, dv = d>>2,
  // stored at f4 = row*8 + ((dv+row)&7).
  __shared__ float ldsk[2][TCHUNK * H_DIM * D_DIM];  // 2 x 8 KB

  const int tid  = threadIdx.x;
  const int lane = tid & 63;
  const int wave = tid >> 6;

  const int bid = blockIdx.x;
  const int b   = bid >> 10;         // 1024 blocks per batch element
  const int rem = bid & 1023;
  const int sg  = rem >> 3;          // s-group 0..127
  const int tq  = rem & 7;           // t-eighth 0..7

  const int h      = lane & 7;
  const int t_sub  = lane >> 3;
  const int s_base = sg * SB + wave * RS;
  const int t0     = tq * (S_DIM / TSPLIT);   // 256 * tq

  // ---- q fragments -> registers (32 VGPRs/row-set, held for block) ----
  f32x4 qf[RS][8];
  {
    const float* qb = q + (size_t)b * S_DIM * (H_DIM * D_DIM);
#pragma unroll
    for (int i = 0; i < RS; ++i) {
      const float* qr = qb + (size_t)(s_base + i) * (H_DIM * D_DIM) + h * D_DIM;
#pragma unroll
      for (int dv = 0; dv < 8; ++dv)
        qf[i][dv] = *(const f32x4*)(qr + dv * 4);
    }
  }

  const float* kb = k + (size_t)b * S_DIM * (H_DIM * D_DIM);

  // Staging: thread handles global f32x4 indices g4 = tid, tid+256
  // (coalesced). Swizzled LDS dest: f4 = (row<<3) | ((dv+row)&7).
  const int g4a = tid;
  const int g4b = tid + 256;
  const int f4a = ((g4a >> 3) << 3) | (((g4a & 7) + (g4a >> 3)) & 7);
  const int f4b = ((g4b >> 3) << 3) | (((g4b & 7) + (g4b >> 3)) & 7);

  // Compute-side read addresses: (row=lane, dv) -> loop-invariant.
  int raddr[8];
#pragma unroll
  for (int dv = 0; dv < 8; ++dv)
    raddr[dv] = (lane << 3) | ((dv + lane) & 7);

  // ---- prologue: chunk 0 -> LDS buf 0; chunk 1 -> prefetch regs ----
  f32x4 st0, st1;
  {
    const f32x4* kc0 = (const f32x4*)(kb + (size_t)t0 * (H_DIM * D_DIM));
    st0 = kc0[g4a];
    st1 = kc0[g4b];
    f32x4* b0 = (f32x4*)ldsk[0];
    b0[f4a] = st0;
    b0[f4b] = st1;
    const f32x4* kc1 = (const f32x4*)(kb +
        (size_t)(t0 + TCHUNK) * (H_DIM * D_DIM));
    st0 = kc1[g4a];
    st1 = kc1[g4b];
  }

  const float nscale = -0.17677669529663687f;  // -1/sqrt(32)
  float* optr = out +
      ((size_t)(b * S_DIM + s_base) * S_DIM + (size_t)(t0 + t_sub)) * H_DIM + h;

  for (int c = 0; c < NCH; ++c) {
    __syncthreads();   // prev readers of buf^1 done; buf[c&1] fully written

    if (c + 1 < NCH) {           // stage chunk c+1 from regs into buf^1
      f32x4* nb = (f32x4*)ldsk[(c + 1) & 1];
      nb[f4a] = st0;             // swizzled ds_write_b128, conflict-free
      nb[f4b] = st1;
      if (c + 2 < NCH) {         // register-prefetch chunk c+2
        const f32x4* kn = (const f32x4*)(kb +
            (size_t)(t0 + (c + 2) * TCHUNK) * (H_DIM * D_DIM));
        st0 = kn[g4a];
        st1 = kn[g4b];
      }
    }

    const f32x4* kp = (const f32x4*)ldsk[c & 1];
    float acc0 = 0.f, acc1 = 0.f, acc2 = 0.f, acc3 = 0.f;
#pragma unroll
    for (int dv = 0; dv < 8; ++dv) {
      const f32x4 kf = kp[raddr[dv]];   // swizzled ds_read_b128, conflict-free
      acc0 += __builtin_fabsf(qf[0][dv].x - kf.x) + __builtin_fabsf(qf[0][dv].y - kf.y)
            + __builtin_fabsf(qf[0][dv].z - kf.z) + __builtin_fabsf(qf[0][dv].w - kf.w);
      acc1 += __builtin_fabsf(qf[1][dv].x - kf.x) + __builtin_fabsf(qf[1][dv].y - kf.y)
            + __builtin_fabsf(qf[1][dv].z - kf.z) + __builtin_fabsf(qf[1][dv].w - kf.w);
      acc2 += __builtin_fabsf(qf[2][dv].x - kf.x) + __builtin_fabsf(qf[2][dv].y - kf.y)
            + __builtin_fabsf(qf[2][dv].z - kf.z) + __builtin_fabsf(qf[2][dv].w - kf.w);
      acc3 += __builtin_fabsf(qf[3][dv].x - kf.x) + __builtin_fabsf(qf[3][dv].y - kf.y)
            + __builtin_fabsf(qf[3][dv].z - kf.z) + __builtin_fabsf(qf[3][dv].w - kf.w);
    }

    // coalesced dword stores: consecutive lanes -> consecutive (t,h) addrs
    float* o = optr + (size_t)c * (TCHUNK * H_DIM);
    o[0]                         = acc0 * nscale;
    o[(size_t)1 * S_DIM * H_DIM] = acc1 * nscale;
    o[(size_t)2 * S_DIM * H_DIM] = acc2 * nscale;
    o[(size_t)3 * S_DIM * H_DIM] = acc3 * nscale;
  }
}

extern "C" void kernel_launch(void* const* d_in, const int* in_sizes, int n_in,
                              void* d_out, int out_size, void* d_ws, size_t ws_size,
                              hipStream_t stream) {
  const float* q = (const float*)d_in[0];
  const float* k = (const float*)d_in[1];
  float* out = (float*)d_out;
  const int B = 2;
  dim3 grid(B * (S_DIM / SB) * TSPLIT);   // 2048 blocks
  dim3 block(NTHREADS);
  l1attn_kernel<<<grid, block, 0, stream>>>(q, k, out);
}